// Round 10
// baseline (237.248 us; speedup 1.0000x reference)
//
#include <hip/hip_runtime.h>
#include <hip/hip_bf16.h>
#include <stdint.h>

#define Bn 64
#define Nn 25
#define Cn 128
#define Tn 256
#define EPSC 1e-5f

typedef short bf16x8 __attribute__((ext_vector_type(8)));
typedef float f32x4 __attribute__((ext_vector_type(4)));
typedef int   i32x4 __attribute__((ext_vector_type(4)));

// ws layout
static constexpr size_t X2T_BYTES  = (size_t)Bn * Nn * Tn * Cn * 2;  // 104,857,600
static constexpr size_t WEFF_OFF   = X2T_BYTES;
static constexpr size_t WEFF_BYTES = (size_t)3 * 128 * 128 * 2;      // 98,304
static constexpr size_t EPI_OFF    = WEFF_OFF + WEFF_BYTES;
static constexpr size_t ROWSUM_OFF = EPI_OFF + (size_t)7 * 128 * 4;
static constexpr size_t ZPAGE_OFF  = ROWSUM_OFF + 256;   // 256 B zeros (DMA src for halo)
static constexpr size_t WS_NEEDED  = ZPAGE_OFF + 256;

__device__ __forceinline__ uint16_t f2bf(float f) {
    uint32_t u = __builtin_bit_cast(uint32_t, f);
    u = (u + 0x7FFFu + ((u >> 16) & 1u)) >> 16;  // RNE
    return (uint16_t)u;
}

// async global->LDS DMA, 16B per lane; LDS dest = wave-uniform base + lane*16
__device__ __forceinline__ void dma16(const void* gsrc, void* ldst) {
    __builtin_amdgcn_global_load_lds(
        (const __attribute__((address_space(1))) unsigned int*)gsrc,
        (__attribute__((address_space(3))) unsigned int*)ldst, 16, 0, 0);
}

// ---------------------------------------------------------------------------
// prep: Weff[k][o][c] = sum_i Wc[o,i,k] * Wg[i,c]  (bf16), epilogue tables,
// rowsum, zero page. grid 385 x 128
// ---------------------------------------------------------------------------
__global__ __launch_bounds__(128) void prep_kernel(
    const float* __restrict__ adj, const float* __restrict__ Wg,
    const float* __restrict__ bg,  const float* __restrict__ Wc,
    const float* __restrict__ bc,
    const float* __restrict__ tg,  const float* __restrict__ tb_,
    const float* __restrict__ tm,  const float* __restrict__ tv,
    const float* __restrict__ bng, const float* __restrict__ bnb,
    const float* __restrict__ bnm, const float* __restrict__ bnv,
    uint16_t* __restrict__ weff, float* __restrict__ epi, float* __restrict__ rowsum,
    uint32_t* __restrict__ zpage)
{
    int blk = blockIdx.x;
    int tid = threadIdx.x;
    if (blk < 384) {
        int k = blk >> 7, o = blk & 127;
        float acc = 0.f;
        for (int i = 0; i < 128; ++i) {
            float wc = Wc[(o * 128 + i) * 3 + k];
            acc = fmaf(wc, Wg[i * 128 + tid], acc);
        }
        weff[((size_t)(k * 128 + o)) * 128 + tid] = f2bf(acc);
    } else {
        int o = tid;
        float b0 = 0.f, b1 = 0.f, b2 = 0.f;
        for (int i = 0; i < 128; ++i) {
            float g = bg[i];
            b0 = fmaf(Wc[(o * 128 + i) * 3 + 0], g, b0);
            b1 = fmaf(Wc[(o * 128 + i) * 3 + 1], g, b1);
            b2 = fmaf(Wc[(o * 128 + i) * 3 + 2], g, b2);
        }
        float a1  = tg[o] * rsqrtf(tv[o] + EPSC);
        float c1p = tb_[o] - a1 * tm[o] + a1 * bc[o];
        float a2  = bng[o] * rsqrtf(bnv[o] + EPSC);
        float c2  = bnb[o] - a2 * bnm[o];
        epi[0 * 128 + o] = a1;
        epi[1 * 128 + o] = c1p;
        epi[2 * 128 + o] = a2;
        epi[3 * 128 + o] = c2;
        epi[4 * 128 + o] = a1 * b0;
        epi[5 * 128 + o] = a1 * b1;
        epi[6 * 128 + o] = a1 * b2;
        if (tid < Nn) {
            float s = 0.f;
            for (int n = 0; n < Nn; ++n) s += adj[tid * Nn + n];
            rowsum[tid] = s;
        }
        if (tid < 64) zpage[tid] = 0u;
    }
}

// ---------------------------------------------------------------------------
// adjmix: x2T[b][m][t][c] (bf16) = sum_n adj[m,n] * x[b][n][c][t]
// 32c x 32t tile. Transpose tail is WAVE-PRIVATE (zero barriers): wave w owns
// the 8-channel oct c0+8w..+7 for all 32 t; it writes its acc slice to its own
// LDS slab and reads it back transposed in the same wave (lgkmcnt orders it,
// no __syncthreads needed). Double-buffered per m-pair. grid 2048 x 256.
// ---------------------------------------------------------------------------
__global__ __launch_bounds__(256) void adjmix_kernel(
    const float* __restrict__ x, const float* __restrict__ adj,
    uint16_t* __restrict__ x2t)
{
    __shared__ float adjs[Nn * Nn];
    __shared__ float trw[4][2][2][8][36];   // [wave][buf][mhalf][lc][t(+pad)]

    int bid = blockIdx.x;
    int b  = bid >> 5;
    int rem = bid & 31;
    int cb = rem >> 3, tb = rem & 7;
    int c0 = cb * 32, t0 = tb * 32;
    int tid = threadIdx.x;

    for (int i = tid; i < Nn * Nn; i += 256) adjs[i] = adj[i];
    __syncthreads();

    int cl = tid >> 3;          // 0..31 (channel row within tile)
    int t4 = (tid & 7) * 4;     // 0..28 (t, 4 per thread)

    float acc[Nn][4];
#pragma unroll
    for (int m = 0; m < Nn; ++m)
#pragma unroll
        for (int j = 0; j < 4; ++j) acc[m][j] = 0.f;

    for (int n = 0; n < Nn; ++n) {
        const float4 v = *reinterpret_cast<const float4*>(
            x + (((size_t)(b * Nn + n) * Cn + c0 + cl) * Tn + t0 + t4));
#pragma unroll
        for (int m = 0; m < Nn; ++m) {
            float a = adjs[m * Nn + n];
            acc[m][0] = fmaf(a, v.x, acc[m][0]);
            acc[m][1] = fmaf(a, v.y, acc[m][1]);
            acc[m][2] = fmaf(a, v.z, acc[m][2]);
            acc[m][3] = fmaf(a, v.w, acc[m][3]);
        }
    }

    // ---- wave-private transpose + pack + store (no barriers) ----
    int w  = tid >> 6;          // wave id: owns c-oct c0 + 8w .. +7
    int l  = tid & 63;
    int lc = cl & 7;            // local c-row within the wave's oct (0..7)
    int h  = l >> 5;            // 0: m0, 1: m1
    int tt = l & 31;            // t within tile for the read/store phase

#pragma unroll
    for (int p = 0; p < 13; ++p) {
        int m0  = 2 * p;
        int buf = p & 1;
        // write own slice (both m-halves) — [lc][t4..t4+3], 16B aligned
        *reinterpret_cast<f32x4*>(&trw[w][buf][0][lc][t4]) =
            (f32x4){acc[m0][0], acc[m0][1], acc[m0][2], acc[m0][3]};
        if (m0 + 1 < Nn)
            *reinterpret_cast<f32x4*>(&trw[w][buf][1][lc][t4]) =
                (f32x4){acc[m0 + 1][0], acc[m0 + 1][1], acc[m0 + 1][2], acc[m0 + 1][3]};
        // read transposed (same wave wrote it; compiler inserts lgkmcnt)
        int mm = m0 + h;
        if (mm < Nn) {
            i32x4 u;
#pragma unroll
            for (int k2 = 0; k2 < 4; ++k2) {
                uint32_t lo16 = f2bf(trw[w][buf][h][2 * k2 + 0][tt]);
                uint32_t hi16 = f2bf(trw[w][buf][h][2 * k2 + 1][tt]);
                u[k2] = (int)(lo16 | (hi16 << 16));
            }
            size_t elem = ((size_t)(b * Nn + mm) * Tn + (t0 + tt)) * Cn + c0 + 8 * w;
            *reinterpret_cast<i32x4*>(x2t + elem) = u;
        }
    }
}

// ---------------------------------------------------------------------------
// conv: block = (b, m, t-half of 128). ONE barrier per block:
//   stage the whole 130-row slab (t-half + halos, 33280 B LDS, single buffer)
//   in 9 DMA rounds -> vmcnt(0) + __syncthreads -> 4 tiles of MFMA + residual
//   + fused epilogue run FREE (no fences, full unroll: compiler pipelines
//   across tiles). Cross-block stage/compute overlap via 4 blocks/CU
//   co-residency (LDS 33 KB). r5/r8/r9's per-tile barriers were the limiter.
// LAUNCH-BOUNDS RULE (r4/r6/r7): must stay (256,2); min-waves>=3 => spill.
// grid 3200.
// ---------------------------------------------------------------------------
__global__ __launch_bounds__(256, 2) void conv_kernel(
    const uint16_t* __restrict__ x2t, const uint16_t* __restrict__ weff,
    const float* __restrict__ x, const float* __restrict__ epi,
    const float* __restrict__ rowsum, const char* __restrict__ zpage,
    float* __restrict__ out)
{
    constexpr int ROWB = 256;            // bytes per LDS row (128 bf16)
    __shared__ uint16_t lds[130 * 128];  // 33280 B, single buffer
    char* ldsb = (char*)lds;

    int bid = blockIdx.x;                // 3200 = 1600 (b,m) x 2 halves
    int bm  = bid >> 1;
    int th  = bid & 1;
    int m   = bm % Nn;
    int T0  = th * 128;

    int tid = threadIdx.x;
    int w  = tid >> 6;
    int l  = tid & 63;
    int lo = l & 15;
    int hi = l >> 4;
    int o0 = w * 32;

    const char*  xp2 = (const char*)x2t + (size_t)bm * Tn * Cn * 2;
    const short* wp  = (const short*)weff;

    // ---- stage whole slab: rows T0-1 .. T0+128 (130 rows), linear LDS,
    //      source pre-swizzled: LDS chunk cg holds global chunk cg^(r&7) ----
#pragma unroll
    for (int p = 0; p < 9; ++p) {
        int chunk = p * 256 + tid;
        if (chunk < 2080) {
            int lrow = chunk >> 4, cg = chunk & 15;
            int gt = T0 - 1 + lrow;
            int sc = cg ^ (lrow & 7);
            const char* src = (gt >= 0 && gt < Tn)
                ? xp2 + ((size_t)gt * Cn + sc * 8) * 2
                : zpage + sc * 16;
            dma16(src, ldsb + lrow * ROWB + cg * 16);
        }
    }

    // ---- hoist all 24 weight B-frags (96 VGPR) while DMA is in flight ----
    bf16x8 bw[3][4][2];
#pragma unroll
    for (int kk = 0; kk < 3; ++kk)
#pragma unroll
        for (int cc = 0; cc < 4; ++cc)
#pragma unroll
            for (int f = 0; f < 2; ++f) {
                int o = o0 + f * 16 + lo;
                bw[kk][cc][f] = *reinterpret_cast<const bf16x8*>(
                    wp + ((size_t)(kk * 128 + o)) * 128 + cc * 32 + hi * 8);
            }

    // ---- epilogue tables ----
    float a1[2], c1[2], a2[2], c2v[2], g0[2], g1[2], g2[2];
#pragma unroll
    for (int f = 0; f < 2; ++f) {
        int o = o0 + f * 16 + lo;
        a1[f]  = epi[0 * 128 + o];
        c1[f]  = epi[1 * 128 + o];
        a2[f]  = epi[2 * 128 + o];
        c2v[f] = epi[3 * 128 + o];
        g0[f]  = epi[4 * 128 + o];
        g1[f]  = epi[5 * 128 + o];
        g2[f]  = epi[6 * 128 + o];
    }
    float rs = rowsum[m];
    const size_t obase = (size_t)bm * Cn;

    // the ONE sync point of the block
    asm volatile("s_waitcnt vmcnt(0)" ::: "memory");
    __syncthreads();

    // ---- 4 tiles, free-running: no barriers, no fences ----
#pragma unroll
    for (int tq4 = 0; tq4 < 4; ++tq4) {
        int tq = T0 + tq4 * 32;

        f32x4 r4[2][2];
        size_t idx4[2][2];
#pragma unroll
        for (int j = 0; j < 2; ++j)
#pragma unroll
            for (int f = 0; f < 2; ++f) {
                int o   = o0 + f * 16 + lo;
                int tb4 = tq + j * 16 + hi * 4;
                idx4[j][f] = (obase + o) * Tn + tb4;
                r4[j][f] = *reinterpret_cast<const f32x4*>(x + idx4[j][f]);
            }

        f32x4 acc[2][2];
#pragma unroll
        for (int j = 0; j < 2; ++j)
#pragma unroll
            for (int f = 0; f < 2; ++f) acc[j][f] = (f32x4){0.f, 0.f, 0.f, 0.f};

#pragma unroll
        for (int kk = 0; kk < 3; ++kk)
#pragma unroll
            for (int cc = 0; cc < 4; ++cc) {
                bf16x8 af[2];
#pragma unroll
                for (int j = 0; j < 2; ++j) {
                    int lrow  = tq4 * 32 + j * 16 + lo + kk;   // 0..129
                    int lbyte = lrow * ROWB +
                                ((cc * 64 + hi * 16) ^ ((lrow & 7) << 4));
                    af[j] = *reinterpret_cast<const bf16x8*>(ldsb + lbyte);
                }
#pragma unroll
                for (int j = 0; j < 2; ++j)
#pragma unroll
                    for (int f = 0; f < 2; ++f)
                        acc[j][f] = __builtin_amdgcn_mfma_f32_16x16x32_bf16(
                            af[j], bw[kk][cc][f], acc[j][f], 0, 0, 0);
            }

#pragma unroll
        for (int j = 0; j < 2; ++j)
#pragma unroll
            for (int f = 0; f < 2; ++f) {
                int tb4 = tq + j * 16 + hi * 4;
                f32x4 ov;
#pragma unroll
                for (int qq = 0; qq < 4; ++qq) {
                    int t = tb4 + qq;
                    float gbv = g1[f];
                    if (t > 0)      gbv += g0[f];
                    if (t < Tn - 1) gbv += g2[f];
                    float z = fmaxf(fmaf(a1[f], acc[j][f][qq], fmaf(rs, gbv, c1[f])), 0.f);
                    ov[qq] = fmaxf(fmaf(a2[f], z + r4[j][f][qq], c2v[f]), 0.f);
                }
                *reinterpret_cast<f32x4*>(out + idx4[j][f]) = ov;
            }
    }
}

// ---------------------------------------------------------------------------
extern "C" void kernel_launch(void* const* d_in, const int* in_sizes, int n_in,
                              void* d_out, int out_size, void* d_ws, size_t ws_size,
                              hipStream_t stream) {
    const float* x    = (const float*)d_in[0];
    const float* adj  = (const float*)d_in[1];
    const float* Wg   = (const float*)d_in[2];
    const float* bg   = (const float*)d_in[3];
    const float* Wc   = (const float*)d_in[4];
    const float* bc   = (const float*)d_in[5];
    const float* tg   = (const float*)d_in[6];
    const float* tb_  = (const float*)d_in[7];
    const float* tm   = (const float*)d_in[8];
    const float* tv   = (const float*)d_in[9];
    const float* bng  = (const float*)d_in[10];
    const float* bnb  = (const float*)d_in[11];
    const float* bnm  = (const float*)d_in[12];
    const float* bnv  = (const float*)d_in[13];

    if (ws_size < WS_NEEDED) return;

    char* ws = (char*)d_ws;
    uint16_t* x2t    = (uint16_t*)ws;
    uint16_t* weff   = (uint16_t*)(ws + WEFF_OFF);
    float*    epi    = (float*)(ws + EPI_OFF);
    float*    rowsum = (float*)(ws + ROWSUM_OFF);
    char*     zpage  = ws + ZPAGE_OFF;
    float*    out    = (float*)d_out;

    prep_kernel<<<385, 128, 0, stream>>>(adj, Wg, bg, Wc, bc, tg, tb_, tm, tv,
                                         bng, bnb, bnm, bnv, weff, epi, rowsum,
                                         (uint32_t*)zpage);
    adjmix_kernel<<<2048, 256, 0, stream>>>(x, adj, x2t);
    conv_kernel<<<Bn * Nn * 2, 256, 0, stream>>>(x2t, weff, x, epi, rowsum, zpage, out);
}